// Round 2
// baseline (363.526 us; speedup 1.0000x reference)
//
#include <hip/hip_runtime.h>
#include <hip/hip_bf16.h>
#include <cstdint>
#include <cstddef>

// Problem constants
#define Bb   2
#define Tt   2048
#define Cc   896
#define Hh   14
#define HKVc 2
#define Dd   64
#define Mm   (Bb * Tt)        // 4096 rows

typedef __attribute__((ext_vector_type(8))) short bfrag8;   // 8 bf16 (4 VGPRs)
typedef __attribute__((ext_vector_type(4))) float facc4;    // 4 f32 acc
typedef unsigned short u16;

__device__ __forceinline__ float bf2f(u16 v) {
    union { unsigned int u; float f; } c; c.u = ((unsigned int)v) << 16; return c.f;
}
__device__ __forceinline__ u16 f2bf(float f) {
    union { float f; unsigned int u; } c; c.f = f;
    unsigned int u = c.u;
    return (u16)((u + 0x7fffu + ((u >> 16) & 1u)) >> 16);  // RNE
}

// ---------------------------------------------------------------------------
// Kernel 1: fused QKV projection GEMM + bias.  Inputs fp32, ws outputs bf16.
// Block: 256 thr (4 waves). Tile 64(M) x 64(N), K-step 32.
// W staged transposed in LDS as [n][k] (stride 40 elems, 16B-aligned rows).
// ---------------------------------------------------------------------------
__global__ __launch_bounds__(256)
void qkv_kernel(const float* __restrict__ x,
                const float* __restrict__ wq, const float* __restrict__ bq,
                const float* __restrict__ wk, const float* __restrict__ bk,
                const float* __restrict__ wv, const float* __restrict__ bv,
                u16* __restrict__ q_ws, u16* __restrict__ k_ws, u16* __restrict__ v_ws)
{
    __shared__ __align__(16) u16 lds_w[64 * 40];

    const int mt = blockIdx.x;        // 0..63
    const int nt = blockIdx.y;        // 0..17: 14 q-tiles, 2 k-tiles, 2 v-tiles
    const float* W; const float* bias; u16* out; int ldw, col0;
    if (nt < 14)      { W = wq; bias = bq; out = q_ws; ldw = 896; col0 = nt * 64; }
    else if (nt < 16) { W = wk; bias = bk; out = k_ws; ldw = 128; col0 = (nt - 14) * 64; }
    else              { W = wv; bias = bv; out = v_ws; ldw = 128; col0 = (nt - 16) * 64; }

    const int tid  = threadIdx.x;
    const int lane = tid & 63;
    const int wave = tid >> 6;
    const int lr   = lane & 15;       // A-row / B-col / C-col
    const int quad = lane >> 4;       // k-granule selector
    const int row0 = mt * 64 + wave * 16;

    facc4 acc[4];
    #pragma unroll
    for (int i = 0; i < 4; ++i) acc[i] = (facc4){0.f, 0.f, 0.f, 0.f};

    const int sn  = tid & 63;         // staging: LDS row n
    const int skg = (tid >> 6) * 8;   // staging: k-granule base

    for (int k0 = 0; k0 < 896; k0 += 32) {
        __syncthreads();
        {   // coalesced f32 global loads down a W column group, cvt, one b128 LDS write
            union { u16 s[8]; bfrag8 v; } tw;
            #pragma unroll
            for (int j = 0; j < 8; ++j)
                tw.s[j] = f2bf(W[(size_t)(k0 + skg + j) * ldw + col0 + sn]);
            *(bfrag8*)(&lds_w[sn * 40 + skg]) = tw.v;
        }
        __syncthreads();

        // A-frag: 8 consecutive f32 of an x row -> bf16x8
        const float4* ap = (const float4*)(x + (size_t)(row0 + lr) * 896 + k0 + quad * 8);
        const float4 a0 = ap[0], a1 = ap[1];
        union { u16 s[8]; bfrag8 v; } ta;
        ta.s[0] = f2bf(a0.x); ta.s[1] = f2bf(a0.y); ta.s[2] = f2bf(a0.z); ta.s[3] = f2bf(a0.w);
        ta.s[4] = f2bf(a1.x); ta.s[5] = f2bf(a1.y); ta.s[6] = f2bf(a1.z); ta.s[7] = f2bf(a1.w);

        #pragma unroll
        for (int ct = 0; ct < 4; ++ct) {
            const bfrag8 bfr = *(const bfrag8*)(&lds_w[(ct * 16 + lr) * 40 + quad * 8]);
            acc[ct] = __builtin_amdgcn_mfma_f32_16x16x32_bf16(ta.v, bfr, acc[ct], 0, 0, 0);
        }
    }

    // epilogue: bias + store bf16 (C layout: row = quad*4+r, col = lr)
    #pragma unroll
    for (int ct = 0; ct < 4; ++ct) {
        const int col = col0 + ct * 16 + lr;
        const float bb = bias[col];
        #pragma unroll
        for (int r = 0; r < 4; ++r) {
            const int row = row0 + quad * 4 + r;
            out[(size_t)row * ldw + col] = f2bf(acc[ct][r] + bb);
        }
    }
}

// ---------------------------------------------------------------------------
// Kernel 2: RoPE in-place on bf16 q (B,T,H,D) and k (B,T,HKV,D).
// cos/sin tables are fp32. Thread = one (d, d+32) pair.
// ---------------------------------------------------------------------------
__global__ __launch_bounds__(256)
void rope_kernel(u16* __restrict__ q_ws, u16* __restrict__ k_ws,
                 const float* __restrict__ cosT, const float* __restrict__ sinT)
{
    const int NQ = Bb * Tt * Hh * 32;
    const int NK = Bb * Tt * HKVc * 32;
    const int idx = blockIdx.x * 256 + threadIdx.x;

    u16* p; int t, d;
    if (idx < NQ) {
        d = idx & 31;
        const int h = (idx >> 5) % Hh;
        t = (idx / (32 * Hh)) % Tt;
        const int b = idx / (32 * Hh * Tt);
        p = q_ws + ((size_t)(b * Tt + t) * Hh + h) * 64;
    } else if (idx < NQ + NK) {
        const int i = idx - NQ;
        d = i & 31;
        const int h = (i >> 5) % HKVc;
        t = (i / (32 * HKVc)) % Tt;
        const int b = i / (32 * HKVc * Tt);
        p = k_ws + ((size_t)(b * Tt + t) * HKVc + h) * 64;
    } else {
        return;
    }
    const float c1 = cosT[t * 64 + d],      s1 = sinT[t * 64 + d];
    const float c2 = cosT[t * 64 + d + 32], s2 = sinT[t * 64 + d + 32];
    const float a  = bf2f(p[d]);
    const float b2 = bf2f(p[d + 32]);
    p[d]      = f2bf(a * c1 - b2 * s1);   // first half: q*c - q[d+32]*s
    p[d + 32] = f2bf(b2 * c2 + a * s2);   // second half: q*c + q[d-32]*s
}

// ---------------------------------------------------------------------------
// Kernel 3: flash-style causal attention, GQA (kv head = h/7). All-bf16 ws.
// Grid: (T/64) x (B*H). Block 256 thr; wave w owns Q rows qt*64 + w*16 ..+15.
// ---------------------------------------------------------------------------
__global__ __launch_bounds__(256)
void attn_kernel(const u16* __restrict__ q_ws, const u16* __restrict__ k_ws,
                 const u16* __restrict__ v_ws, u16* __restrict__ o_ws)
{
    __shared__ __align__(16) u16 lds_p[4 * 16 * 72];   // per-wave 16x64 P, stride 72
    __shared__ __align__(16) u16 lds_vT[64 * 72];      // [d][j], stride 72

    const int qt = blockIdx.x;            // 0..31
    const int bh = blockIdx.y;            // 0..27
    const int b = bh / Hh, h = bh % Hh;
    const int kvh = h / (Hh / HKVc);      // h / 7

    const int tid  = threadIdx.x;
    const int lane = tid & 63;
    const int wave = tid >> 6;
    const int lr   = lane & 15;
    const int quad = lane >> 4;
    const int m0   = qt * 64 + wave * 16; // q-row base for this wave

    const u16* Qbase = q_ws + (size_t)(b * Tt) * 896 + h * 64;
    const u16* Kbase = k_ws + (size_t)(b * Tt) * 128 + kvh * 64;
    const u16* Vbase = v_ws + (size_t)(b * Tt) * 128 + kvh * 64;

    // Q fragments for both 32-wide k-steps of D=64, held in regs all kernel
    bfrag8 qf[2];
    #pragma unroll
    for (int ks = 0; ks < 2; ++ks)
        qf[ks] = *(const bfrag8*)(Qbase + (size_t)(m0 + lr) * 896 + ks * 32 + quad * 8);

    float m_r[4], l_r[4];
    #pragma unroll
    for (int r = 0; r < 4; ++r) { m_r[r] = -3e38f; l_r[r] = 0.f; }
    facc4 o_acc[4];
    #pragma unroll
    for (int ct = 0; ct < 4; ++ct) o_acc[ct] = (facc4){0.f, 0.f, 0.f, 0.f};

    const float scale = 0.125f;           // 1/sqrt(64)
    const int vd = tid & 63;              // V-staging: this thread's d
    const int vjg = (tid >> 6) * 16;      // and j-granule

    for (int jt = 0; jt <= qt; ++jt) {
        const int j0 = jt * 64;

        __syncthreads();  // previous iter's PV reads done before overwriting V
        {   // stage V^T: 16 coalesced u16 loads + two b128 LDS writes per thread
            union { u16 s[16]; bfrag8 v[2]; } tv;
            #pragma unroll
            for (int j = 0; j < 16; ++j)
                tv.s[j] = Vbase[(size_t)(j0 + vjg + j) * 128 + vd];
            *(bfrag8*)(&lds_vT[vd * 72 + vjg])     = tv.v[0];
            *(bfrag8*)(&lds_vT[vd * 72 + vjg + 8]) = tv.v[1];
        }
        __syncthreads();

        // S = Q K^T  (B-frag of K^T == contiguous-8 along D of K rows)
        facc4 s[4];
        #pragma unroll
        for (int ct = 0; ct < 4; ++ct) {
            s[ct] = (facc4){0.f, 0.f, 0.f, 0.f};
            #pragma unroll
            for (int ks = 0; ks < 2; ++ks) {
                const bfrag8 kf = *(const bfrag8*)(
                    Kbase + (size_t)(j0 + ct * 16 + lr) * 128 + ks * 32 + quad * 8);
                s[ct] = __builtin_amdgcn_mfma_f32_16x16x32_bf16(qf[ks], kf, s[ct], 0, 0, 0);
            }
        }

        // scale + causal mask (only diagonal tile needs per-element mask)
        const bool diag = (jt == qt);
        #pragma unroll
        for (int ct = 0; ct < 4; ++ct) {
            const int j = j0 + ct * 16 + lr;
            #pragma unroll
            for (int r = 0; r < 4; ++r) {
                float sv = s[ct][r] * scale;
                if (diag && j > (m0 + quad * 4 + r)) sv = -3e38f;
                s[ct][r] = sv;
            }
        }

        // online softmax: row max across the quad's 16 lanes
        float alpha[4];
        #pragma unroll
        for (int r = 0; r < 4; ++r) {
            float v = fmaxf(fmaxf(s[0][r], s[1][r]), fmaxf(s[2][r], s[3][r]));
            v = fmaxf(v, __shfl_xor(v, 1));
            v = fmaxf(v, __shfl_xor(v, 2));
            v = fmaxf(v, __shfl_xor(v, 4));
            v = fmaxf(v, __shfl_xor(v, 8));
            const float mn = fmaxf(m_r[r], v);
            alpha[r] = __expf(m_r[r] - mn);
            m_r[r] = mn;
        }

        // P = exp(s - m); write bf16 P to wave-private LDS (C-layout -> [row][col])
        float rsum[4] = {0.f, 0.f, 0.f, 0.f};
        #pragma unroll
        for (int ct = 0; ct < 4; ++ct) {
            #pragma unroll
            for (int r = 0; r < 4; ++r) {
                const float p = __expf(s[ct][r] - m_r[r]);
                rsum[r] += p;
                lds_p[(wave * 16 + quad * 4 + r) * 72 + ct * 16 + lr] = f2bf(p);
            }
        }
        #pragma unroll
        for (int r = 0; r < 4; ++r) {
            float v = rsum[r];
            v += __shfl_xor(v, 1);
            v += __shfl_xor(v, 2);
            v += __shfl_xor(v, 4);
            v += __shfl_xor(v, 8);
            l_r[r] = l_r[r] * alpha[r] + v;
        }
        #pragma unroll
        for (int ct = 0; ct < 4; ++ct)
            #pragma unroll
            for (int r = 0; r < 4; ++r) o_acc[ct][r] *= alpha[r];

        __syncthreads();  // P writes drained before PV fragment reads

        // O += P @ V
        #pragma unroll
        for (int ks = 0; ks < 2; ++ks) {
            const bfrag8 pf = *(const bfrag8*)(&lds_p[(wave * 16 + lr) * 72 + ks * 32 + quad * 8]);
            #pragma unroll
            for (int ct = 0; ct < 4; ++ct) {
                const bfrag8 vf = *(const bfrag8*)(&lds_vT[(ct * 16 + lr) * 72 + ks * 32 + quad * 8]);
                o_acc[ct] = __builtin_amdgcn_mfma_f32_16x16x32_bf16(pf, vf, o_acc[ct], 0, 0, 0);
            }
        }
    }

    // epilogue: O / l -> o_ws[b][t][h*64+d] (bf16)
    #pragma unroll
    for (int ct = 0; ct < 4; ++ct) {
        const int dcol = ct * 16 + lr;
        #pragma unroll
        for (int r = 0; r < 4; ++r) {
            const int t = m0 + quad * 4 + r;
            o_ws[(size_t)(b * Tt + t) * 896 + h * 64 + dcol] = f2bf(o_acc[ct][r] / l_r[r]);
        }
    }
}

// ---------------------------------------------------------------------------
// Kernel 4: output projection  o_ws(4096x896 bf16) @ wo(896x896 f32) -> d_out f32
// ---------------------------------------------------------------------------
__global__ __launch_bounds__(256)
void oproj_kernel(const u16* __restrict__ a_in, const float* __restrict__ wo,
                  float* __restrict__ outp)
{
    __shared__ __align__(16) u16 lds_w[64 * 40];

    const int mt = blockIdx.x;        // 0..63
    const int col0 = blockIdx.y * 64; // 0..13 tiles

    const int tid  = threadIdx.x;
    const int lane = tid & 63;
    const int wave = tid >> 6;
    const int lr   = lane & 15;
    const int quad = lane >> 4;
    const int row0 = mt * 64 + wave * 16;

    facc4 acc[4];
    #pragma unroll
    for (int i = 0; i < 4; ++i) acc[i] = (facc4){0.f, 0.f, 0.f, 0.f};

    const int sn  = tid & 63;
    const int skg = (tid >> 6) * 8;

    for (int k0 = 0; k0 < 896; k0 += 32) {
        __syncthreads();
        {
            union { u16 s[8]; bfrag8 v; } tw;
            #pragma unroll
            for (int j = 0; j < 8; ++j)
                tw.s[j] = f2bf(wo[(size_t)(k0 + skg + j) * 896 + col0 + sn]);
            *(bfrag8*)(&lds_w[sn * 40 + skg]) = tw.v;
        }
        __syncthreads();

        const bfrag8 a = *(const bfrag8*)(a_in + (size_t)(row0 + lr) * 896 + k0 + quad * 8);
        #pragma unroll
        for (int ct = 0; ct < 4; ++ct) {
            const bfrag8 bfr = *(const bfrag8*)(&lds_w[(ct * 16 + lr) * 40 + quad * 8]);
            acc[ct] = __builtin_amdgcn_mfma_f32_16x16x32_bf16(a, bfr, acc[ct], 0, 0, 0);
        }
    }

    #pragma unroll
    for (int ct = 0; ct < 4; ++ct) {
        const int col = col0 + ct * 16 + lr;
        #pragma unroll
        for (int r = 0; r < 4; ++r) {
            const int row = row0 + quad * 4 + r;
            outp[(size_t)row * 896 + col] = acc[ct][r];
        }
    }
}

// ---------------------------------------------------------------------------
extern "C" void kernel_launch(void* const* d_in, const int* in_sizes, int n_in,
                              void* d_out, int out_size, void* d_ws, size_t ws_size,
                              hipStream_t stream)
{
    const float* x    = (const float*)d_in[0];
    const float* wq   = (const float*)d_in[1];
    const float* bq   = (const float*)d_in[2];
    const float* wk   = (const float*)d_in[3];
    const float* bk   = (const float*)d_in[4];
    const float* wv   = (const float*)d_in[5];
    const float* bv   = (const float*)d_in[6];
    const float* wo   = (const float*)d_in[7];
    const float* cosT = (const float*)d_in[8];
    const float* sinT = (const float*)d_in[9];
    // d_in[10] = mask: exact causal tril(0 / -1e9) — applied inline in attn_kernel.

    // Workspace layout (bf16), total exactly 16 MiB:
    u16* q_ws = (u16*)d_ws;                              // 4096*896
    u16* k_ws = q_ws + (size_t)Mm * 896;                 // 4096*128
    u16* v_ws = k_ws + (size_t)Mm * 128;                 // 4096*128
    u16* o_ws = v_ws + (size_t)Mm * 128;                 // 4096*896

    qkv_kernel<<<dim3(64, 18), 256, 0, stream>>>(x, wq, bq, wk, bk, wv, bv,
                                                 q_ws, k_ws, v_ws);
    rope_kernel<<<dim3(8192), 256, 0, stream>>>(q_ws, k_ws, cosT, sinT);
    attn_kernel<<<dim3(32, 28), 256, 0, stream>>>(q_ws, k_ws, v_ws, o_ws);
    oproj_kernel<<<dim3(64, 14), 256, 0, stream>>>(o_ws, wo, (u16*)d_out ? (float*)d_out : (float*)d_out);
}